// Round 4
// baseline (638.784 us; speedup 1.0000x reference)
//
#include <hip/hip_runtime.h>

// ArDCA loss: loss = -sum_{m,i} W[m] * log_softmax(h[i,:] + sum_{j<i} J[i,j,:,X[m,j]])[X[m,i]]
//             + 1e-6 * sum h^2 + 1e-4 * sum_{j<i} J^2
// M=8192, L=256, Q=21. Output: single fp32 scalar.
//
// R8: latency attack. R4(f16,412us) vs R7(fp8,430us) showed ~equal time under
// opposite pipe mixes -> neither LDS nor VALU throughput is the bound; the
// per-chunk stage->barrier->gather->barrier serialization is (global staging
// latency naked between barriers, 2 barriers/chunk, 69k block-chunks).
// Changes:
//  - Register prefetch (T14): chunk k+1's J row is loaded into 21 VGPRs while
//    chunk k is gathered; encode+LDS-write happens next iteration. Global
//    latency hides under gather+barrier.
//  - Double-buffered LDS (2 x 252 rows x 24 B = 12.1 KB): ONE barrier per
//    chunk. A wave at barrier(k+1) has finished gather(k) in program order,
//    so iter k+2's write to buf[k&1] is race-free.
//  - JC 16 -> 12: NROWS=252 <= 256 so every thread stages <=1 row (uniform
//    21-reg prefetch, no double-row threads).
// Carried: fp8-e4m3 rows (24 B, x256 pre-scale vs denormal cliff, f32x2 acc,
// 3x ds_read_b64 at 24-B stride = 2-way-max bank classes), reg terms on
// blockIdx.x==0 (J^2 from prefetched fp32, h^2 in epilogue).
// Spill watch: live set ~75-85 VGPR; if WRITE_SIZE balloons again, trim regs.

#define M_SEQ 8192
#define L_POS 256
#define Q_SYM 21
#define QQ    441
#define JC    12
#define NROWS (JC * Q_SYM)       // 252 rows; 252*24 B = 6048 B per buffer

typedef float f32x2 __attribute__((ext_vector_type(2)));

__device__ __forceinline__ float wave_block_reduce(float v, float* red, int tid) {
    #pragma unroll
    for (int off = 32; off > 0; off >>= 1) v += __shfl_down(v, off, 64);
    if ((tid & 63) == 0) red[tid >> 6] = v;
    __syncthreads();
    return red[0] + red[1] + red[2] + red[3];
}

__global__ void zero_out(float* __restrict__ out) { out[0] = 0.0f; }

// One block per (m-chunk of 256, i). Each thread owns one m.
__global__ __launch_bounds__(256) void pair_nll_kernel(const int* __restrict__ X,
                                                       const float* __restrict__ W,
                                                       const float* __restrict__ h,
                                                       const float* __restrict__ J,
                                                       float* __restrict__ out) {
    __shared__ uint2 JL[2][NROWS * 3];   // 2 x 6048 B
    __shared__ float red[4];

    const int tid = threadIdx.x;
    const int i  = blockIdx.y;
    const int m  = blockIdx.x * 256 + tid;
    const bool do_reg = (blockIdx.x == 0);
    const int* xrow = X + (size_t)m * L_POS;

    // staging assignment: thread tid owns row tid = (jc0, b0); tid>=252 idle
    const int jc0 = tid / Q_SYM;
    const int b0  = tid - jc0 * Q_SYM;
    const bool stager = (tid < NROWS);

    f32x2 acc[11];
    #pragma unroll
    for (int k = 0; k < 11; ++k) { acc[k].x = 0.0f; acc[k].y = 0.0f; }
    float regsum = 0.0f;
    float pv[Q_SYM];                     // prefetched J row (fp32)
    #pragma unroll
    for (int a = 0; a < Q_SYM; ++a) pv[a] = 0.0f;

    const int nch = (i + JC - 1) / JC;

    // ---- prefetch chunk 0
    if (nch > 0 && stager && jc0 < i) {
        const float* s = J + ((size_t)i * L_POS + jc0) * QQ + b0;
        float rs = 0.0f;
        #pragma unroll
        for (int a = 0; a < Q_SYM; ++a) { pv[a] = s[a * Q_SYM]; }
        if (do_reg) {
            #pragma unroll
            for (int a = 0; a < Q_SYM; ++a) rs += pv[a] * pv[a];
            regsum += rs;
        }
    }

    for (int k = 0; k < nch; ++k) {
        const int j0 = k * JC;

        // ---- encode prefetched row -> LDS buf[k&1] (3 ds_write_b64)
        if (stager) {
            const float S = 256.0f;
            unsigned int d[6];
            #pragma unroll
            for (int g = 0; g < 5; ++g) {
                int t = __builtin_amdgcn_cvt_pk_fp8_f32(pv[4*g+0] * S, pv[4*g+1] * S, 0, false);
                t     = __builtin_amdgcn_cvt_pk_fp8_f32(pv[4*g+2] * S, pv[4*g+3] * S, t, true);
                d[g] = (unsigned int)t;
            }
            d[5] = (unsigned int)__builtin_amdgcn_cvt_pk_fp8_f32(pv[20] * S, 0.0f, 0, false);
            uint2* dst = &JL[k & 1][tid * 3];
            dst[0] = make_uint2(d[0], d[1]);
            dst[1] = make_uint2(d[2], d[3]);
            dst[2] = make_uint2(d[4], d[5]);
        }

        // ---- current chunk's X values (block-uniform guards keep loads in-bounds)
        int4 xA = *(const int4*)(xrow + j0);                       // j0 <= 252, +3 ok
        int4 xB = make_int4(0, 0, 0, 0), xC = make_int4(0, 0, 0, 0);
        if (j0 + 4 < i) xB = *(const int4*)(xrow + j0 + 4);        // then j0 <= 240
        if (j0 + 8 < i) xC = *(const int4*)(xrow + j0 + 8);

        // ---- prefetch next chunk's J row (latency hides under barrier+gather)
        if (k + 1 < nch && stager && (j0 + JC + jc0) < i) {
            const float* s = J + ((size_t)i * L_POS + j0 + JC + jc0) * QQ + b0;
            float rs = 0.0f;
            #pragma unroll
            for (int a = 0; a < Q_SYM; ++a) { pv[a] = s[a * Q_SYM]; }
            if (do_reg) {
                #pragma unroll
                for (int a = 0; a < Q_SYM; ++a) rs += pv[a] * pv[a];
                regsum += rs;
            }
        }

        __syncthreads();   // staged writes visible; sole barrier this chunk

        int xv[JC] = {xA.x, xA.y, xA.z, xA.w, xB.x, xB.y, xB.z, xB.w,
                      xC.x, xC.y, xC.z, xC.w};

        const uint2* buf = JL[k & 1];
        #pragma unroll
        for (int jc = 0; jc < JC; ++jc) {
            if (j0 + jc < i) {   // block-uniform guard (scalar branch)
                int b = xv[jc];
                const uint2* r = buf + (jc * Q_SYM + b) * 3;
                uint2 q0 = r[0];
                uint2 q1 = r[1];
                uint2 q2 = r[2];
                acc[0]  += __builtin_amdgcn_cvt_pk_f32_fp8((int)q0.x, false);
                acc[1]  += __builtin_amdgcn_cvt_pk_f32_fp8((int)q0.x, true);
                acc[2]  += __builtin_amdgcn_cvt_pk_f32_fp8((int)q0.y, false);
                acc[3]  += __builtin_amdgcn_cvt_pk_f32_fp8((int)q0.y, true);
                acc[4]  += __builtin_amdgcn_cvt_pk_f32_fp8((int)q1.x, false);
                acc[5]  += __builtin_amdgcn_cvt_pk_f32_fp8((int)q1.x, true);
                acc[6]  += __builtin_amdgcn_cvt_pk_f32_fp8((int)q1.y, false);
                acc[7]  += __builtin_amdgcn_cvt_pk_f32_fp8((int)q1.y, true);
                acc[8]  += __builtin_amdgcn_cvt_pk_f32_fp8((int)q2.x, false);
                acc[9]  += __builtin_amdgcn_cvt_pk_f32_fp8((int)q2.x, true);
                acc[10] += __builtin_amdgcn_cvt_pk_f32_fp8((int)q2.y, false);
            }
        }
        // no trailing barrier: next iter writes the other buffer; writes to
        // this buffer recur only after barrier(k+1), by which point every
        // wave has finished this gather (program order).
    }

    // ---- logits = h[i,:] + pair/256 ; log-softmax ; pick gold = X[m,i]
    const float* hrow = h + i * Q_SYM;
    const float INV = 0.00390625f;   // 1/256: undo the fp8 encode pre-scale
    float logits[Q_SYM];
    #pragma unroll
    for (int k = 0; k < 10; ++k) {
        logits[2 * k]     = hrow[2 * k]     + acc[k].x * INV;
        logits[2 * k + 1] = hrow[2 * k + 1] + acc[k].y * INV;
    }
    logits[20] = hrow[20] + acc[10].x * INV;

    float mx = -3.4e38f;
    #pragma unroll
    for (int a = 0; a < Q_SYM; ++a) mx = fmaxf(mx, logits[a]);
    float s = 0.0f;
    #pragma unroll
    for (int a = 0; a < Q_SYM; ++a) s += __expf(logits[a] - mx);
    int g = xrow[i];
    float gold = 0.0f;
    #pragma unroll
    for (int a = 0; a < Q_SYM; ++a) gold = (a == g) ? logits[a] : gold;
    float logp = gold - mx - __logf(s);
    float v = -W[m] * logp;

    // ---- fold regularization terms (blockIdx.x==0 blocks only)
    if (do_reg) {
        v += 1e-4f * regsum;
        if (tid < Q_SYM) {
            float hv = hrow[tid];
            v += 1e-6f * hv * hv;
        }
    }

    __syncthreads();   // LDS reuse safety before reduction
    float tot = wave_block_reduce(v, red, tid);
    if (tid == 0) atomicAdd(out, tot);
}

extern "C" void kernel_launch(void* const* d_in, const int* in_sizes, int n_in,
                              void* d_out, int out_size, void* d_ws, size_t ws_size,
                              hipStream_t stream) {
    const int*   X = (const int*)d_in[0];
    const float* W = (const float*)d_in[1];
    const float* h = (const float*)d_in[2];
    const float* J = (const float*)d_in[3];
    float* out = (float*)d_out;

    hipLaunchKernelGGL(zero_out, dim3(1), dim3(1), 0, stream, out);
    dim3 grid(M_SEQ / 256, L_POS);
    hipLaunchKernelGGL(pair_nll_kernel, grid, dim3(256), 0, stream, X, W, h, J, out);
}

// Round 5
// 608.162 us; speedup vs baseline: 1.0504x; 1.0504x over previous
//
#include <hip/hip_runtime.h>

// ArDCA loss: loss = -sum_{m,i} W[m] * log_softmax(h[i,:] + sum_{j<i} J[i,j,:,X[m,j]])[X[m,i]]
//             + 1e-6 * sum h^2 + 1e-4 * sum_{j<i} J^2
// M=8192, L=256, Q=21. Output: single fp32 scalar.
//
// R9: split-pipeline. R4/R7/R8 all sit ~2.3x above pipe throughput floors;
// the shared cost is per-chunk staging (21 strided global loads + encode)
// naked between barriers. R8's register-prefetch fix busted the 64-VGPR
// occupancy boundary (72 VGPR -> 32% occ, 550us). New structure:
//  - Kernel A: transcode lower-tri J (57.6 MB) -> J8 in d_ws (16.7 MB):
//    J8[pair(i,j)][b][a] = e4m3(J[i][j][a][b] * 256), rows padded to 24 B,
//    pair blocks padded to 512 B, triangular-packed. Also computes the
//    1e-4*sumJ^2 + 1e-6*sumh^2 reg terms (removed from kernel B).
//  - Kernel B: staging = 2 unconditional global_load_lds dwordx4 issues per
//    thread (chunk = 16 pairs * 512 B = 8192 B, lane-linear LDS dest,
//    wave-uniform base per guide). No encode VALU, no staging VGPRs.
//    Double-buffered LDS, ONE __syncthreads per chunk (its implicit
//    vmcnt(0)+lgkmcnt(0) drain is exactly the arrival wait we need; loads
//    for chunk k+1 stay in flight across the gather of chunk k).
//  - Gather unchanged from R7: 3x ds_read_b64 per j at 24-B row stride
//    inside 512-B pair blocks -> bank-pair class 3b mod 16, max 2-way
//    (free). R7's staging-write 4-way conflicts are gone entirely.
// VGPR watch: no prefetch regs, no regsum -> ~55 expected; must stay <=64.
// ws requirement: 32640*512 + 8192 = 16.72 MB.

#define M_SEQ 8192
#define L_POS 256
#define Q_SYM 21
#define QQ    441
#define JC    16
#define NPAIR 32640                  // 256*255/2
#define PAIRB 512                    // padded bytes per (i,j) pair in J8
#define CHUNKB (JC * PAIRB)          // 8192 B staged per chunk
#define PPB   16                     // pairs per transcode block

typedef float f32x2 __attribute__((ext_vector_type(2)));

__device__ __forceinline__ float wave_block_reduce(float v, float* red, int tid) {
    #pragma unroll
    for (int off = 32; off > 0; off >>= 1) v += __shfl_down(v, off, 64);
    if ((tid & 63) == 0) red[tid >> 6] = v;
    __syncthreads();
    return red[0] + red[1] + red[2] + red[3];
}

__device__ __forceinline__ void gload16(const void* g, void* l) {
    __builtin_amdgcn_global_load_lds(
        (const __attribute__((address_space(1))) unsigned int*)g,
        (__attribute__((address_space(3))) unsigned int*)l, 16, 0, 0);
}

__global__ void zero_out(float* __restrict__ out) { out[0] = 0.0f; }

// ---- Kernel A: J[i][j][a][b] (fp32) -> J8[pair][b][a] (e4m3 of J*256),
//      lower triangle only, + reg terms.
__global__ __launch_bounds__(256) void transcode_kernel(const float* __restrict__ J,
                                                        const float* __restrict__ h,
                                                        unsigned char* __restrict__ J8,
                                                        float* __restrict__ out) {
    __shared__ unsigned char enc[PAIRB];
    __shared__ float red[4];
    const int tid = threadIdx.x;

    const int p0 = blockIdx.x * PPB;
    // decode pair p0 -> (ii, jj), then walk forward
    int ii = (int)((1.0f + sqrtf((float)(8 * p0 + 1))) * 0.5f);
    while (ii * (ii - 1) / 2 > p0) --ii;
    while ((ii + 1) * ii / 2 <= p0) ++ii;
    int jj = p0 - ii * (ii - 1) / 2;

    float rs = 0.0f;
    for (int p = p0; p < p0 + PPB; ++p) {
        __syncthreads();                       // enc reuse: prev pair's readers done
        if (tid < 128) ((uint32_t*)enc)[tid] = 0u;
        __syncthreads();
        const float* src = J + ((size_t)ii * L_POS + jj) * QQ;
        #pragma unroll
        for (int r = 0; r < 2; ++r) {
            int t = tid + r * 256;
            if (t < QQ) {
                float v = src[t];              // coalesced: contiguous 1764 B
                rs += v * v;
                int a = t / Q_SYM, b = t - a * Q_SYM;
                int e = __builtin_amdgcn_cvt_pk_fp8_f32(v * 256.0f, 0.0f, 0, false);
                enc[b * 24 + a] = (unsigned char)(e & 0xff);
            }
        }
        __syncthreads();
        if (tid < 128)
            ((uint32_t*)(J8 + (size_t)p * PAIRB))[tid] = ((const uint32_t*)enc)[tid];
        ++jj; if (jj == ii) { jj = 0; ++ii; }
    }

    float acc = 1e-4f * rs;
    if (blockIdx.x == 0) {                     // fold h^2 once
        float hs = 0.0f;
        for (int t = tid; t < L_POS * Q_SYM; t += 256) { float v = h[t]; hs += v * v; }
        acc += 1e-6f * hs;
    }
    __syncthreads();
    float tot = wave_block_reduce(acc, red, tid);
    if (tid == 0) atomicAdd(out, tot);
}

// ---- Kernel B: one block per (m-chunk of 256, i). Each thread owns one m.
__global__ __launch_bounds__(256) void pair_nll_kernel(const int* __restrict__ X,
                                                       const float* __restrict__ W,
                                                       const float* __restrict__ h,
                                                       const unsigned char* __restrict__ J8,
                                                       float* __restrict__ out) {
    __shared__ unsigned char JL[2][CHUNKB];    // 2 x 8192 B
    __shared__ float red[4];

    const int tid = threadIdx.x;
    const int i  = blockIdx.y;
    const int m  = blockIdx.x * 256 + tid;
    const int* xrow = X + (size_t)m * L_POS;
    const unsigned char* jbase = J8 + ((size_t)i * (i - 1) / 2) * PAIRB;

    f32x2 acc[11];
    #pragma unroll
    for (int k = 0; k < 11; ++k) { acc[k].x = 0.0f; acc[k].y = 0.0f; }

    const int nch = (i + JC - 1) / JC;
    const int wbase = (tid >> 6) << 10;        // wave-uniform LDS base offset

    if (nch > 0) {                             // issue chunk 0 (2 full wave-issues/thread)
        const unsigned char* g = jbase + tid * 16;
        gload16(g,        &JL[0][wbase]);
        gload16(g + 4096, &JL[0][4096 + wbase]);
    }
    __syncthreads();                           // implicit vmcnt(0): chunk 0 arrived

    for (int k = 0; k < nch; ++k) {
        const int j0 = k * JC;

        // ---- issue chunk k+1 into the other buffer (stays in flight over gather)
        if (k + 1 < nch) {
            const unsigned char* g = jbase + (size_t)(k + 1) * CHUNKB + tid * 16;
            gload16(g,        &JL[(k + 1) & 1][wbase]);
            gload16(g + 4096, &JL[(k + 1) & 1][4096 + wbase]);
        }

        // ---- this thread's 16 X values (block-uniform guards keep loads in-bounds)
        int4 xA = *(const int4*)(xrow + j0);
        int4 xB = make_int4(0,0,0,0), xC = make_int4(0,0,0,0), xD = make_int4(0,0,0,0);
        if (j0 + 4  < i) xB = *(const int4*)(xrow + j0 + 4);
        if (j0 + 8  < i) xC = *(const int4*)(xrow + j0 + 8);
        if (j0 + 12 < i) xD = *(const int4*)(xrow + j0 + 12);
        int xv[JC] = {xA.x, xA.y, xA.z, xA.w, xB.x, xB.y, xB.z, xB.w,
                      xC.x, xC.y, xC.z, xC.w, xD.x, xD.y, xD.z, xD.w};

        const unsigned char* buf = JL[k & 1];
        #pragma unroll
        for (int jc = 0; jc < JC; ++jc) {
            if (j0 + jc < i) {                 // block-uniform guard
                int b = xv[jc];
                const uint2* r = (const uint2*)(buf + (jc << 9) + b * 24);
                uint2 q0 = r[0];
                uint2 q1 = r[1];
                uint2 q2 = r[2];
                acc[0]  += __builtin_amdgcn_cvt_pk_f32_fp8((int)q0.x, false);
                acc[1]  += __builtin_amdgcn_cvt_pk_f32_fp8((int)q0.x, true);
                acc[2]  += __builtin_amdgcn_cvt_pk_f32_fp8((int)q0.y, false);
                acc[3]  += __builtin_amdgcn_cvt_pk_f32_fp8((int)q0.y, true);
                acc[4]  += __builtin_amdgcn_cvt_pk_f32_fp8((int)q1.x, false);
                acc[5]  += __builtin_amdgcn_cvt_pk_f32_fp8((int)q1.x, true);
                acc[6]  += __builtin_amdgcn_cvt_pk_f32_fp8((int)q1.y, false);
                acc[7]  += __builtin_amdgcn_cvt_pk_f32_fp8((int)q1.y, true);
                acc[8]  += __builtin_amdgcn_cvt_pk_f32_fp8((int)q2.x, false);
                acc[9]  += __builtin_amdgcn_cvt_pk_f32_fp8((int)q2.x, true);
                acc[10] += __builtin_amdgcn_cvt_pk_f32_fp8((int)q2.y, false);
            }
        }

        // one barrier per chunk: drains vmcnt(0) (chunk k+1 arrived) and joins
        // all waves' reads of buf[k&1] before iter k+2 overwrites it.
        __syncthreads();
    }

    // ---- logits = h[i,:] + pair/256 ; log-softmax ; pick gold = X[m,i]
    const float* hrow = h + i * Q_SYM;
    const float INV = 0.00390625f;             // 1/256: undo fp8 encode pre-scale
    float logits[Q_SYM];
    #pragma unroll
    for (int k = 0; k < 10; ++k) {
        logits[2 * k]     = hrow[2 * k]     + acc[k].x * INV;
        logits[2 * k + 1] = hrow[2 * k + 1] + acc[k].y * INV;
    }
    logits[20] = hrow[20] + acc[10].x * INV;

    float mx = -3.4e38f;
    #pragma unroll
    for (int a = 0; a < Q_SYM; ++a) mx = fmaxf(mx, logits[a]);
    float s = 0.0f;
    #pragma unroll
    for (int a = 0; a < Q_SYM; ++a) s += __expf(logits[a] - mx);
    int g = xrow[i];
    float gold = 0.0f;
    #pragma unroll
    for (int a = 0; a < Q_SYM; ++a) gold = (a == g) ? logits[a] : gold;
    float logp = gold - mx - __logf(s);
    float v = -W[m] * logp;

    float tot = wave_block_reduce(v, red, tid);
    if (tid == 0) atomicAdd(out, tot);
}

extern "C" void kernel_launch(void* const* d_in, const int* in_sizes, int n_in,
                              void* d_out, int out_size, void* d_ws, size_t ws_size,
                              hipStream_t stream) {
    const int*   X = (const int*)d_in[0];
    const float* W = (const float*)d_in[1];
    const float* h = (const float*)d_in[2];
    const float* J = (const float*)d_in[3];
    float* out = (float*)d_out;
    unsigned char* J8 = (unsigned char*)d_ws;  // needs 32640*512 + 8192 = 16.72 MB

    hipLaunchKernelGGL(zero_out, dim3(1), dim3(1), 0, stream, out);
    hipLaunchKernelGGL(transcode_kernel, dim3(NPAIR / PPB), dim3(256), 0, stream,
                       J, h, J8, out);
    dim3 grid(M_SEQ / 256, L_POS);
    hipLaunchKernelGGL(pair_nll_kernel, grid, dim3(256), 0, stream, X, W, h, J8, out);
}

// Round 6
// 486.725 us; speedup vs baseline: 1.3124x; 1.2495x over previous
//
#include <hip/hip_runtime.h>

// ArDCA loss: loss = -sum_{m,i} W[m] * log_softmax(h[i,:] + sum_{j<i} J[i,j,:,X[m,j]])[X[m,i]]
//             + 1e-6 * sum h^2 + 1e-4 * sum_{j<i} J^2
// M=8192, L=256, Q=21. Output: single fp32 scalar.
//
// R10: R9's split-pipeline structure + f16 payload (decode-free gather).
// R9 post-mortem: staging became free (FETCH 235->70 MB) but VALUBusy hit 90%
// -> the fp8 decode stream (11 cvt_pk_f32_fp8 + 11 pk_add_f32 per j, ~245
// issue-cyc/wave-j) is a VALU wall. R4's f16 path measured ~67 cyc/wave-j
// (11 pk_add_f16, zero decode). So:
//  - Kernel A: transcode lower-tri J -> f16 J8[pair][b][a] rows of 21 f16
//    padded to 48 B; pair block padded to 1024 B; triangular-packed 33.4 MB
//    in d_ws. Reg terms (1e-4 J^2 + 1e-6 h^2) folded here.
//  - Kernel B: stage via 3x global_load_lds dwordx4 per thread per 12-pair
//    chunk (12288 B, lane-linear dest), double-buffered, ONE barrier/chunk
//    (implicit vmcnt(0) drain = arrival wait). Gather = 3x ds_read_b128 +
//    10 v_pk_add_f16 + 1 half add per j. No decode, no encode, no staging
//    VGPRs. f16 accumulate = R4's exact numerics (absmax was 0).
//  - Accepted cost: b128@48-B rows -> (3b+p) mod 8 quad classes, max 3/class
//    (~6.5e7 conflicts, R4-measured) — LDS pipe has headroom vs the VALU wall.
// VGPR watch: ~50 expected, must stay <=64. ws: 32640*1024 = 33.4 MB.

#define M_SEQ 8192
#define L_POS 256
#define Q_SYM 21
#define QQ    441
#define JC    12
#define NPAIR 32640                  // 256*255/2
#define PAIRB 1024                   // padded bytes per (i,j) pair in J8
#define CHUNKB (JC * PAIRB)          // 12288 B staged per chunk
#define PPB   16                     // pairs per transcode block

typedef _Float16 h2 __attribute__((ext_vector_type(2)));

__device__ __forceinline__ h2 as_h2(unsigned int u) {
    union { unsigned int u; h2 h; } c; c.u = u; return c.h;
}

__device__ __forceinline__ float wave_block_reduce(float v, float* red, int tid) {
    #pragma unroll
    for (int off = 32; off > 0; off >>= 1) v += __shfl_down(v, off, 64);
    if ((tid & 63) == 0) red[tid >> 6] = v;
    __syncthreads();
    return red[0] + red[1] + red[2] + red[3];
}

__device__ __forceinline__ void gload16(const void* g, void* l) {
    __builtin_amdgcn_global_load_lds(
        (const __attribute__((address_space(1))) unsigned int*)g,
        (__attribute__((address_space(3))) unsigned int*)l, 16, 0, 0);
}

__global__ void zero_out(float* __restrict__ out) { out[0] = 0.0f; }

// ---- Kernel A: J[i][j][a][b] (fp32, lower tri) -> J8[pair][b][a] (f16),
//      rows padded to 48 B, pair block padded to 1024 B. + reg terms.
__global__ __launch_bounds__(256) void transcode_kernel(const float* __restrict__ J,
                                                        const float* __restrict__ h,
                                                        unsigned char* __restrict__ J8,
                                                        float* __restrict__ out) {
    __shared__ unsigned char enc[PAIRB];
    __shared__ float red[4];
    const int tid = threadIdx.x;

    const int p0 = blockIdx.x * PPB;
    // decode pair p0 -> (ii, jj), then walk forward
    int ii = (int)((1.0f + sqrtf((float)(8 * p0 + 1))) * 0.5f);
    while (ii * (ii - 1) / 2 > p0) --ii;
    while ((ii + 1) * ii / 2 <= p0) ++ii;
    int jj = p0 - ii * (ii - 1) / 2;

    float rs = 0.0f;
    for (int p = p0; p < p0 + PPB; ++p) {
        __syncthreads();                       // enc reuse: prev pair's copy done
        ((uint32_t*)enc)[tid] = 0u;            // zero all 1024 B (pads)
        __syncthreads();
        const float* src = J + ((size_t)ii * L_POS + jj) * QQ;
        #pragma unroll
        for (int r = 0; r < 2; ++r) {
            int t = tid + r * 256;
            if (t < QQ) {
                float v = src[t];              // coalesced: contiguous 1764 B
                rs += v * v;
                int a = t / Q_SYM, b = t - a * Q_SYM;
                *((_Float16*)(enc + b * 48 + 2 * a)) = (_Float16)v;
            }
        }
        __syncthreads();
        ((uint32_t*)(J8 + (size_t)p * PAIRB))[tid] = ((const uint32_t*)enc)[tid];
        ++jj; if (jj == ii) { jj = 0; ++ii; }
    }

    float acc = 1e-4f * rs;
    if (blockIdx.x == 0) {                     // fold h^2 once
        float hs = 0.0f;
        for (int t = tid; t < L_POS * Q_SYM; t += 256) { float v = h[t]; hs += v * v; }
        acc += 1e-6f * hs;
    }
    __syncthreads();
    float tot = wave_block_reduce(acc, red, tid);
    if (tid == 0) atomicAdd(out, tot);
}

// ---- Kernel B: one block per (m-chunk of 256, i). Each thread owns one m.
__global__ __launch_bounds__(256) void pair_nll_kernel(const int* __restrict__ X,
                                                       const float* __restrict__ W,
                                                       const float* __restrict__ h,
                                                       const unsigned char* __restrict__ J8,
                                                       float* __restrict__ out) {
    __shared__ unsigned char JL[2][CHUNKB];    // 2 x 12288 B
    __shared__ float red[4];

    const int tid = threadIdx.x;
    const int i  = blockIdx.y;
    const int m  = blockIdx.x * 256 + tid;
    const int* xrow = X + (size_t)m * L_POS;
    const unsigned char* jbase = J8 + ((size_t)i * (i - 1) / 2) * PAIRB;

    h2 acc[10];
    #pragma unroll
    for (int k = 0; k < 10; ++k) { acc[k].x = (_Float16)0.f; acc[k].y = (_Float16)0.f; }
    _Float16 acc20 = (_Float16)0.f;

    const int nch = (i + JC - 1) / JC;
    const int wbase = (tid >> 6) << 10;        // wave-uniform LDS base offset

    if (nch > 0) {                             // issue chunk 0 (3 issues/thread)
        const unsigned char* g = jbase + tid * 16;
        gload16(g,        &JL[0][wbase]);
        gload16(g + 4096, &JL[0][4096 + wbase]);
        gload16(g + 8192, &JL[0][8192 + wbase]);
    }
    __syncthreads();                           // implicit vmcnt(0): chunk 0 arrived

    for (int k = 0; k < nch; ++k) {
        const int j0 = k * JC;

        // ---- issue chunk k+1 into the other buffer (in flight over gather)
        if (k + 1 < nch) {
            const unsigned char* g = jbase + (size_t)(k + 1) * CHUNKB + tid * 16;
            unsigned char* l = &JL[(k + 1) & 1][wbase];
            gload16(g,        l);
            gload16(g + 4096, l + 4096);
            gload16(g + 8192, l + 8192);
        }

        // ---- this thread's 12 X values (block-uniform guards keep loads in-bounds)
        int4 xA = *(const int4*)(xrow + j0);
        int4 xB = make_int4(0,0,0,0), xC = make_int4(0,0,0,0);
        if (j0 + 4 < i) xB = *(const int4*)(xrow + j0 + 4);
        if (j0 + 8 < i) xC = *(const int4*)(xrow + j0 + 8);
        int xv[JC] = {xA.x, xA.y, xA.z, xA.w, xB.x, xB.y, xB.z, xB.w,
                      xC.x, xC.y, xC.z, xC.w};

        const unsigned char* buf = JL[k & 1];
        #pragma unroll
        for (int jc = 0; jc < JC; ++jc) {
            if (j0 + jc < i) {                 // block-uniform guard
                int b = xv[jc];
                const uint4* r = (const uint4*)(buf + (jc << 10) + b * 48);
                uint4 f0 = r[0];               // a0..a7
                uint4 f1 = r[1];               // a8..a15
                uint4 f2 = r[2];               // a16..a20 + pad
                acc[0] += as_h2(f0.x); acc[1] += as_h2(f0.y);
                acc[2] += as_h2(f0.z); acc[3] += as_h2(f0.w);
                acc[4] += as_h2(f1.x); acc[5] += as_h2(f1.y);
                acc[6] += as_h2(f1.z); acc[7] += as_h2(f1.w);
                acc[8] += as_h2(f2.x); acc[9] += as_h2(f2.y);
                acc20  += as_h2(f2.z).x;
            }
        }

        // one barrier per chunk: drains vmcnt(0) (chunk k+1 arrived) and joins
        // all waves' reads of buf[k&1] before iter k+2 overwrites it.
        __syncthreads();
    }

    // ---- logits = h[i,:] + pair ; log-softmax ; pick gold = X[m,i]
    const float* hrow = h + i * Q_SYM;
    float logits[Q_SYM];
    #pragma unroll
    for (int k = 0; k < 10; ++k) {
        logits[2 * k]     = hrow[2 * k]     + (float)acc[k].x;
        logits[2 * k + 1] = hrow[2 * k + 1] + (float)acc[k].y;
    }
    logits[20] = hrow[20] + (float)acc20;

    float mx = -3.4e38f;
    #pragma unroll
    for (int a = 0; a < Q_SYM; ++a) mx = fmaxf(mx, logits[a]);
    float s = 0.0f;
    #pragma unroll
    for (int a = 0; a < Q_SYM; ++a) s += __expf(logits[a] - mx);
    int g = xrow[i];
    float gold = 0.0f;
    #pragma unroll
    for (int a = 0; a < Q_SYM; ++a) gold = (a == g) ? logits[a] : gold;
    float logp = gold - mx - __logf(s);
    float v = -W[m] * logp;

    float tot = wave_block_reduce(v, red, tid);
    if (tid == 0) atomicAdd(out, tot);
}

extern "C" void kernel_launch(void* const* d_in, const int* in_sizes, int n_in,
                              void* d_out, int out_size, void* d_ws, size_t ws_size,
                              hipStream_t stream) {
    const int*   X = (const int*)d_in[0];
    const float* W = (const float*)d_in[1];
    const float* h = (const float*)d_in[2];
    const float* J = (const float*)d_in[3];
    float* out = (float*)d_out;
    unsigned char* J8 = (unsigned char*)d_ws;  // needs 32640*1024 = 33.4 MB

    hipLaunchKernelGGL(zero_out, dim3(1), dim3(1), 0, stream, out);
    hipLaunchKernelGGL(transcode_kernel, dim3(NPAIR / PPB), dim3(256), 0, stream,
                       J, h, J8, out);
    dim3 grid(M_SEQ / 256, L_POS);
    hipLaunchKernelGGL(pair_nll_kernel, grid, dim3(256), 0, stream, X, W, h, J8, out);
}